// Round 2
// baseline (435.195 us; speedup 1.0000x reference)
//
#include <hip/hip_runtime.h>
#include <math.h>

typedef unsigned short u16;
typedef unsigned int u32;
typedef __bf16 bf16x8 __attribute__((ext_vector_type(8)));
typedef float f32x4 __attribute__((ext_vector_type(4)));

__device__ __forceinline__ float bf2f(u16 v){ union{u32 u;float f;}c; c.u=((u32)v)<<16; return c.f; }
__device__ __forceinline__ u16 f2bf(float f){ union{float f;u32 u;}c; c.f=f; u32 l=(c.u>>16)&1u; c.u+=0x7fffu+l; return (u16)(c.u>>16); }
__device__ __forceinline__ u32 pk2(float a, float b){ return (u32)f2bf(a) | ((u32)f2bf(b)<<16); }
// load 8 consecutive f32 (32B-aligned) -> 8 bf16 packed in uint4
__device__ __forceinline__ uint4 ld8f(const float* p){
  float4 x = ((const float4*)p)[0];
  float4 y = ((const float4*)p)[1];
  uint4 r; r.x=pk2(x.x,x.y); r.y=pk2(x.z,x.w); r.z=pk2(y.x,y.y); r.w=pk2(y.z,y.w);
  return r;
}

// ---------------- setup kernels ----------------

// scatter rbf_e1 (f32 -> bf16) and sph_e1[:,1] into e2 ordering
__global__ void k_setup_edges(const int* __restrict__ e1_to_e2,
                              const float* __restrict__ rbf_e1,
                              const float* __restrict__ sph_e1,
                              u16* __restrict__ rbf1p,
                              float* __restrict__ sph_c, int E1) {
  int e = blockIdx.x*256 + threadIdx.x;
  if (e >= E1) return;
  int f = e1_to_e2[e];
  sph_c[f] = sph_e1[e*3+1];
  const float* s = rbf_e1 + (size_t)e*32;
  uint4* d = (uint4*)(rbf1p + (size_t)f*32);
  d[0]=ld8f(s); d[1]=ld8f(s+8); d[2]=ld8f(s+16); d[3]=ld8f(s+24);
}

// CSR row pointers over (already key-sorted) e2
__global__ void k_out_ptr(const int* __restrict__ src2, int* __restrict__ out_ptr,
                          int Nn, int E2) {
  int n = blockIdx.x*256 + threadIdx.x;
  if (n > Nn) return;
  int lo=0, hi=E2;
  while (lo<hi){ int m=(lo+hi)>>1; if (src2[m]<n) lo=m+1; else hi=m; }
  out_ptr[n]=lo;
}

// assemble padded transposed big weight: WbigT[n(384)][k(448)] (bf16 from f32 w1)
__global__ void k_wbigt(const float* __restrict__ w1, u16* __restrict__ WbigT) {
  int id = blockIdx.x*256+threadIdx.x;
  if (id >= 384*448) return;
  int n = id/448, k = id%448;
  int q = n>>7, nn = n&127;
  int row = -1;
  if (k<128) row = q*128+k;                                    // t_e2[f] -> Q1/Q2/P3
  else if (k<256) { if (q==0) row = 384+(k-128); }             // h[src] -> Q1
  else if (k<384) { if (q==0) row = 512+(k-256); else if (q==1) row = 640+(k-256); } // h[dst]
  else if (k<416) { if (q==0) row = 768+(k-384); else if (q==1) row = 800+(k-384); } // rbf_e1
  else { if (q==2) row = 832+(k-416); }                        // rbf_e2 -> P3
  WbigT[id] = (row>=0) ? f2bf(w1[row*128+nn]) : (u16)0;
}

// WcT = (w2 @ wgw)^T (bf16), bc2 = b2 @ wgw (f32), WgtT = wgt^T (bf16)
__global__ void k_smallw(const float* __restrict__ w2, const float* __restrict__ wgw,
                         const float* __restrict__ wgt, const float* __restrict__ b2,
                         u16* __restrict__ WcT, u16* __restrict__ WgtT,
                         float* __restrict__ bc2) {
  int id = blockIdx.x*256+threadIdx.x;
  if (id < 16384) {
    int n = id&127, k = id>>7;
    float s = 0.f;
    for (int r=0;r<128;r++) s += w2[k*128+r]*wgw[r*128+n];
    WcT[n*128+k] = f2bf(s);
    WgtT[n*128+k] = f2bf(wgt[k*128+n]);
  } else if (id < 16384+128) {
    int n = id-16384;
    float s = 0.f;
    for (int r=0;r<128;r++) s += b2[r]*wgw[r*128+n];
    bc2[n] = s;
  }
}

// ---------------- MFMA GEMM (templated) ----------------
// MODE 0: K=448 gathered f32 A (converted) -> Q1/Q2/P3 bf16 (blockIdx.y selects; +b1 for P3)
// MODE 1: K=128 A=S(bf16),  B=WcT  -> G = sigmoid(S@Wc + cnt*bc2 + bgw)  (bf16)
// MODE 2: K=128 A=t_e2(f32),B=WgtT -> out = t_e2 + G * tanh(t_e2@wgt + bgt)  (f32)
struct GArgs {
  const float* t_f32; const float* h; const float* rbf_e2;
  const u16* rbf1p; const u16* Asrc;
  const int* src2; const int* dst2; const int* cnt;
  const u16* Bmat; const u16* Gin;
  const float* b1; const float* bgw; const float* bgt; const float* bc2;
  u16* out0; u16* out1; u16* out2;
  float* outf;
  int M;
};

template<int MODE>
__global__ __launch_bounds__(256, 2)
void k_gemm(GArgs a) {
  constexpr int KT = (MODE==0)?448:128;
  constexpr int NK = KT/32;
  __shared__ u16 As[128*40];
  __shared__ u16 Bs[128*40];
  const int tid = threadIdx.x;
  const int bm = blockIdx.x, bn = blockIdx.y;
  const int lane = tid & 63, wave = tid >> 6;
  const int wm = wave >> 1, wn = wave & 1;
  const int quad = lane >> 4, l16 = lane & 15;

  const int part = tid & 3;        // k-subchunk (8 elems)
  const int ra = tid >> 2;         // rows handled by this thread
  const int rb = ra + 64;
  long fa = (long)bm*128 + ra;
  long fb = (long)bm*128 + rb;
  if (fa >= a.M) fa = a.M-1;
  if (fb >= a.M) fb = a.M-1;
  int sa=0, da=0, sb=0, db=0;
  if constexpr (MODE==0) { sa=a.src2[fa]; da=a.dst2[fa]; sb=a.src2[fb]; db=a.dst2[fb]; }

  f32x4 acc[4][4] = {};
  for (int ks=0; ks<NK; ks++) {
    const int kb = ks*32;
    uint4 va, vb;
    if constexpr (MODE==0) {
      if (ks<4)       { va = ld8f(a.t_f32 + fa*128 + kb + part*8);
                        vb = ld8f(a.t_f32 + fb*128 + kb + part*8); }
      else if (ks<8)  { va = ld8f(a.h + (long)sa*128 + (kb-128) + part*8);
                        vb = ld8f(a.h + (long)sb*128 + (kb-128) + part*8); }
      else if (ks<12) { va = ld8f(a.h + (long)da*128 + (kb-256) + part*8);
                        vb = ld8f(a.h + (long)db*128 + (kb-256) + part*8); }
      else if (ks==12){ va = *(const uint4*)(a.rbf1p + fa*32 + part*8);
                        vb = *(const uint4*)(a.rbf1p + fb*32 + part*8); }
      else            { va = ld8f(a.rbf_e2 + fa*32 + part*8);
                        vb = ld8f(a.rbf_e2 + fb*32 + part*8); }
    } else if constexpr (MODE==1) {
      va = *(const uint4*)(a.Asrc + fa*128 + kb + part*8);
      vb = *(const uint4*)(a.Asrc + fb*128 + kb + part*8);
    } else {
      va = ld8f(a.t_f32 + fa*128 + kb + part*8);
      vb = ld8f(a.t_f32 + fb*128 + kb + part*8);
    }
    uint4 wa = *(const uint4*)(a.Bmat + (long)(bn*128 + ra)*KT + kb + part*8);
    uint4 wb = *(const uint4*)(a.Bmat + (long)(bn*128 + rb)*KT + kb + part*8);
    __syncthreads();
    *(uint4*)(As + ra*40 + part*8) = va;
    *(uint4*)(As + rb*40 + part*8) = vb;
    *(uint4*)(Bs + ra*40 + part*8) = wa;
    *(uint4*)(Bs + rb*40 + part*8) = wb;
    __syncthreads();
    bf16x8 af[4], bfr[4];
    #pragma unroll
    for (int t=0;t<4;t++) {
      af[t]  = *(const bf16x8*)(As + (wm*64 + t*16 + l16)*40 + quad*8);
      bfr[t] = *(const bf16x8*)(Bs + (wn*64 + t*16 + l16)*40 + quad*8);
    }
    #pragma unroll
    for (int tm=0;tm<4;tm++)
      #pragma unroll
      for (int tn=0;tn<4;tn++)
        acc[tm][tn] = __builtin_amdgcn_mfma_f32_16x16x32_bf16(af[tm], bfr[tn], acc[tm][tn], 0,0,0);
  }

  // epilogue (C/D: col=lane&15, row=quad*4+reg)
  #pragma unroll
  for (int tm=0;tm<4;tm++) {
    const int rloc = wm*64 + tm*16 + quad*4;
    #pragma unroll
    for (int r=0;r<4;r++) {
      long row = (long)bm*128 + rloc + r;
      if (row >= a.M) continue;
      #pragma unroll
      for (int tn=0;tn<4;tn++) {
        const int col = wn*64 + tn*16 + l16;
        float v = acc[tm][tn][r];
        if constexpr (MODE==0) {
          u16* dst = (bn==0)? a.out0 : (bn==1)? a.out1 : a.out2;
          if (bn==2) v += a.b1[col];
          dst[row*128 + col] = f2bf(v);
        } else if constexpr (MODE==1) {
          float u = v + (float)a.cnt[row]*a.bc2[col] + a.bgw[col];
          float g = 1.f/(1.f+expf(-u));
          a.out0[row*128+col] = f2bf(g);
        } else {
          float vv = v + a.bgt[col];
          float th = 1.f - 2.f/(expf(2.f*vv)+1.f);
          float t  = a.t_f32[row*128+col];
          float g  = bf2f(a.Gin[row*128+col]);
          a.outf[row*128+col] = t + g*th;
        }
      }
    }
  }
}

// ---------------- wedge accumulation ----------------
// one wave per e2 edge (i,j): S[eij] = sum over k of silu(Q1[ik]+Q2[kj]+P3[ij]+c*w1[864])
// NOTE: S may alias P3 (each wave reads only its own P3 row, then writes S row).
__global__ __launch_bounds__(256, 4)
void k_wedge(const u16* __restrict__ Q1, const u16* __restrict__ Q2,
             const u16* __restrict__ P3, const float* __restrict__ sph_c,
             const int* __restrict__ src2, const int* __restrict__ dst2,
             const int* __restrict__ out_ptr, const float* __restrict__ w1,
             u16* __restrict__ S, int* __restrict__ cnt, int E2) {
  int gw = (int)((blockIdx.x*256 + threadIdx.x) >> 6);
  int lane = threadIdx.x & 63;
  if (gw >= E2) return;
  int i = src2[gw], j = dst2[gw];
  u32 p3u = ((const u32*)(P3 + (size_t)gw*128))[lane];
  float p30 = bf2f((u16)(p3u&0xffff)), p31 = bf2f((u16)(p3u>>16));
  float2 wv = ((const float2*)(w1 + 864*128))[lane];
  float w0 = wv.x, w1f = wv.y;
  float a0=0.f, a1=0.f; int c=0;
  int beg = out_ptr[i], end = out_ptr[i+1];
  for (int f=beg; f<end; ++f) {
    int k = dst2[f];
    int lo = out_ptr[k], hi = out_ptr[k+1];
    int hi0 = hi;
    while (lo<hi) { int m=(lo+hi)>>1; if (dst2[m]<j) lo=m+1; else hi=m; }
    if (lo < hi0 && dst2[lo]==j) {
      float cf = sph_c[f]*sph_c[lo];
      u32 q1u = ((const u32*)(Q1 + (size_t)f*128))[lane];
      u32 q2u = ((const u32*)(Q2 + (size_t)lo*128))[lane];
      float x0 = p30 + bf2f((u16)(q1u&0xffff)) + bf2f((u16)(q2u&0xffff)) + cf*w0;
      float x1 = p31 + bf2f((u16)(q1u>>16))    + bf2f((u16)(q2u>>16))    + cf*w1f;
      a0 += x0/(1.f+expf(-x0));
      a1 += x1/(1.f+expf(-x1));
      c++;
    }
  }
  u32 outp = ((u32)f2bf(a1)<<16) | (u32)f2bf(a0);
  ((u32*)(S + (size_t)gw*128))[lane] = outp;
  if (lane==0) cnt[gw]=c;
}

// ---------------- launch ----------------
extern "C" void kernel_launch(void* const* d_in, const int* in_sizes, int n_in,
                              void* d_out, int out_size, void* d_ws, size_t ws_size,
                              hipStream_t stream) {
  const float* t_e2  = (const float*)d_in[0];
  const float* h     = (const float*)d_in[1];
  const int* ei2     = (const int*)d_in[3];
  const int* e1_to_e2 = (const int*)d_in[4];
  const float* rbf_e1 = (const float*)d_in[7];
  const float* rbf_e2 = (const float*)d_in[8];
  const float* sph_e1 = (const float*)d_in[9];
  const float* w1  = (const float*)d_in[11];
  const float* b1  = (const float*)d_in[12];
  const float* w2  = (const float*)d_in[13];
  const float* b2  = (const float*)d_in[14];
  const float* wgw = (const float*)d_in[15];
  const float* bgw = (const float*)d_in[16];
  const float* wgt = (const float*)d_in[17];
  const float* bgt = (const float*)d_in[18];

  const int E2 = in_sizes[0]/128;
  const int Nn = in_sizes[1]/128;
  const int E1 = in_sizes[5];
  const int* src2 = ei2;
  const int* dst2 = ei2 + E2;

  // workspace carve (16B-aligned regions, ~68 MB total)
  char* p = (char*)d_ws;
  u16* Q1 = (u16*)p;       p += (size_t)E2*128*2;
  u16* Q2 = (u16*)p;       p += (size_t)E2*128*2;
  u16* P3 = (u16*)p;       p += (size_t)E2*128*2;   // aliased as S after wedge
  u16* rbf1p = (u16*)p;    p += (size_t)E2*32*2;
  u16* WbigT = (u16*)p;    p += (size_t)384*448*2;
  u16* WcT   = (u16*)p;    p += (size_t)128*128*2;
  u16* WgtT  = (u16*)p;    p += (size_t)128*128*2;
  float* sph_c = (float*)p; p += (size_t)E2*4;
  float* bc2   = (float*)p; p += 512;
  int* out_ptr = (int*)p;   p += (((size_t)(Nn+1)*4 + 63)/64)*64;
  int* cnt     = (int*)p;   p += (size_t)E2*4;
  u16* S = P3;   // alias: safe (row-local read-then-write in k_wedge)
  u16* G = Q1;   // alias: Q1 dead after wedge stage

  k_setup_edges<<<(E1+255)/256, 256, 0, stream>>>(e1_to_e2, rbf_e1, sph_e1, rbf1p, sph_c, E1);
  k_out_ptr<<<(Nn+1+255)/256, 256, 0, stream>>>(src2, out_ptr, Nn, E2);
  k_wbigt<<<(384*448+255)/256, 256, 0, stream>>>(w1, WbigT);
  k_smallw<<<(16512+255)/256, 256, 0, stream>>>(w2, wgw, wgt, b2, WcT, WgtT, bc2);

  const int Mb = (E2+127)/128;
  {
    GArgs a = {};
    a.t_f32=t_e2; a.h=h; a.rbf1p=rbf1p; a.rbf_e2=rbf_e2;
    a.src2=src2; a.dst2=dst2; a.Bmat=WbigT; a.b1=b1;
    a.out0=Q1; a.out1=Q2; a.out2=P3; a.M=E2;
    k_gemm<0><<<dim3(Mb,3), 256, 0, stream>>>(a);
  }
  k_wedge<<<(E2+3)/4, 256, 0, stream>>>(Q1, Q2, P3, sph_c, src2, dst2, out_ptr, w1, S, cnt, E2);
  {
    GArgs a = {};
    a.Asrc=S; a.cnt=cnt; a.Bmat=WcT; a.bgw=bgw; a.bc2=bc2;
    a.out0=G; a.M=E2;
    k_gemm<1><<<dim3(Mb,1), 256, 0, stream>>>(a);
  }
  {
    GArgs a = {};
    a.t_f32=t_e2; a.Bmat=WgtT; a.bgt=bgt; a.Gin=G;
    a.outf=(float*)d_out; a.M=E2;
    k_gemm<2><<<dim3(Mb,1), 256, 0, stream>>>(a);
  }
}

// Round 3
// 330.066 us; speedup vs baseline: 1.3185x; 1.3185x over previous
//
#include <hip/hip_runtime.h>
#include <math.h>

typedef unsigned short u16;
typedef unsigned int u32;
typedef __bf16 bf16x8 __attribute__((ext_vector_type(8)));
typedef float f32x4 __attribute__((ext_vector_type(4)));

__device__ __forceinline__ float bf2f(u16 v){ union{u32 u;float f;}c; c.u=((u32)v)<<16; return c.f; }
__device__ __forceinline__ u16 f2bf(float f){ union{float f;u32 u;}c; c.f=f; u32 l=(c.u>>16)&1u; c.u+=0x7fffu+l; return (u16)(c.u>>16); }
__device__ __forceinline__ u32 pk2(float a, float b){ return (u32)f2bf(a) | ((u32)f2bf(b)<<16); }
// load 8 consecutive f32 (32B-aligned) -> 8 bf16 packed in uint4
__device__ __forceinline__ uint4 ld8f(const float* p){
  float4 x = ((const float4*)p)[0];
  float4 y = ((const float4*)p)[1];
  uint4 r; r.x=pk2(x.x,x.y); r.y=pk2(x.z,x.w); r.z=pk2(y.x,y.y); r.w=pk2(y.z,y.w);
  return r;
}
__device__ __forceinline__ float fsilu(float x){ return x/(1.f+__expf(-x)); }

// ---------------- setup kernels ----------------

// scatter rbf_e1 (f32 -> bf16) and sph_e1[:,1] into e2 ordering
__global__ void k_setup_edges(const int* __restrict__ e1_to_e2,
                              const float* __restrict__ rbf_e1,
                              const float* __restrict__ sph_e1,
                              u16* __restrict__ rbf1p,
                              float* __restrict__ sph_c, int E1) {
  int e = blockIdx.x*256 + threadIdx.x;
  if (e >= E1) return;
  int f = e1_to_e2[e];
  sph_c[f] = sph_e1[e*3+1];
  const float* s = rbf_e1 + (size_t)e*32;
  uint4* d = (uint4*)(rbf1p + (size_t)f*32);
  d[0]=ld8f(s); d[1]=ld8f(s+8); d[2]=ld8f(s+16); d[3]=ld8f(s+24);
}

// CSR row pointers over (already key-sorted) e2
__global__ void k_out_ptr(const int* __restrict__ src2, int* __restrict__ out_ptr,
                          int Nn, int E2) {
  int n = blockIdx.x*256 + threadIdx.x;
  if (n > Nn) return;
  int lo=0, hi=E2;
  while (lo<hi){ int m=(lo+hi)>>1; if (src2[m]<n) lo=m+1; else hi=m; }
  out_ptr[n]=lo;
}

// assemble padded transposed big weight: WbigT[n(384)][k(448)] (bf16 from f32 w1)
__global__ void k_wbigt(const float* __restrict__ w1, u16* __restrict__ WbigT) {
  int id = blockIdx.x*256+threadIdx.x;
  if (id >= 384*448) return;
  int n = id/448, k = id%448;
  int q = n>>7, nn = n&127;
  int row = -1;
  if (k<128) row = q*128+k;                                    // t_e2[f] -> Q1/Q2/P3
  else if (k<256) { if (q==0) row = 384+(k-128); }             // h[src] -> Q1
  else if (k<384) { if (q==0) row = 512+(k-256); else if (q==1) row = 640+(k-256); } // h[dst]
  else if (k<416) { if (q==0) row = 768+(k-384); else if (q==1) row = 800+(k-384); } // rbf_e1
  else { if (q==2) row = 832+(k-416); }                        // rbf_e2 -> P3
  WbigT[id] = (row>=0) ? f2bf(w1[row*128+nn]) : (u16)0;
}

// WcT = (w2 @ wgw)^T (bf16), bc2 = b2 @ wgw (f32), WgtT = wgt^T (bf16)
__global__ void k_smallw(const float* __restrict__ w2, const float* __restrict__ wgw,
                         const float* __restrict__ wgt, const float* __restrict__ b2,
                         u16* __restrict__ WcT, u16* __restrict__ WgtT,
                         float* __restrict__ bc2) {
  int id = blockIdx.x*256+threadIdx.x;
  if (id < 16384) {
    int n = id&127, k = id>>7;
    float s = 0.f;
    for (int r=0;r<128;r++) s += w2[k*128+r]*wgw[r*128+n];
    WcT[n*128+k] = f2bf(s);
    WgtT[n*128+k] = f2bf(wgt[k*128+n]);
  } else if (id < 16384+128) {
    int n = id-16384;
    float s = 0.f;
    for (int r=0;r<128;r++) s += b2[r]*wgw[r*128+n];
    bc2[n] = s;
  }
}

// ---------------- wedge enumeration (thread-parallel) ----------------
// one thread per (edge, out-candidate): binary search (k,j) in e2, write
// compacted record (f, lo, cf) into wrec[gw*8 + slot]; cnt[gw] = #wedges.
__global__ __launch_bounds__(256, 8)
void k_enum(const int* __restrict__ src2, const int* __restrict__ dst2,
            const int* __restrict__ out_ptr, const float* __restrict__ sph_c,
            int4* __restrict__ wrec, int* __restrict__ cnt, int E2) {
  int id = blockIdx.x*256 + threadIdx.x;
  if (id >= E2*8) return;
  int gw = id >> 3, d = id & 7;
  int i = src2[gw], j = dst2[gw];
  int f = out_ptr[i] + d;
  if (f >= out_ptr[i+1]) return;
  int k = dst2[f];
  int lo = out_ptr[k], hi = out_ptr[k+1], hi0 = hi;
  while (lo<hi) { int m=(lo+hi)>>1; if (dst2[m]<j) lo=m+1; else hi=m; }
  if (lo < hi0 && dst2[lo]==j) {
    float cf = sph_c[f]*sph_c[lo];
    int slot = atomicAdd(&cnt[gw], 1);
    int4 r; r.x=f; r.y=lo; r.z=__float_as_int(cf); r.w=0;
    wrec[(size_t)gw*8 + slot] = r;
  }
}

// ---------------- wedge accumulation ----------------
// one wave per e2 edge: S[gw] = sum_w silu(Q1[f_w]+Q2[lo_w]+P3[gw]+cf_w*w1[864])
// S aliases P3 (row-local read-then-write). 2-way unrolled for load ILP.
__global__ __launch_bounds__(256, 8)
void k_wedge2(const u16* __restrict__ Q1, const u16* __restrict__ Q2,
              const u16* __restrict__ P3, const int4* __restrict__ wrec,
              const int* __restrict__ cnt, const float* __restrict__ w1,
              u16* __restrict__ S, int E2) {
  int gw = (int)((blockIdx.x*256 + threadIdx.x) >> 6);
  int lane = threadIdx.x & 63;
  if (gw >= E2) return;
  u32 p3u = ((const u32*)(P3 + (size_t)gw*128))[lane];
  float p30 = bf2f((u16)(p3u&0xffff)), p31 = bf2f((u16)(p3u>>16));
  float2 wv = ((const float2*)(w1 + 864*128))[lane];
  const u32* q1b = (const u32*)Q1;
  const u32* q2b = (const u32*)Q2;
  const int4* wr = wrec + (size_t)gw*8;
  int c = cnt[gw];
  float a0=0.f, a1=0.f;
  int w = 0;
  for (; w+2<=c; w+=2) {
    int4 rA = wr[w], rB = wr[w+1];
    u32 xA = q1b[(size_t)rA.x*64 + lane];
    u32 yA = q2b[(size_t)rA.y*64 + lane];
    u32 xB = q1b[(size_t)rB.x*64 + lane];
    u32 yB = q2b[(size_t)rB.y*64 + lane];
    float cfA = __int_as_float(rA.z), cfB = __int_as_float(rB.z);
    float x0 = p30 + bf2f((u16)(xA&0xffff)) + bf2f((u16)(yA&0xffff)) + cfA*wv.x;
    float x1 = p31 + bf2f((u16)(xA>>16))    + bf2f((u16)(yA>>16))    + cfA*wv.y;
    float z0 = p30 + bf2f((u16)(xB&0xffff)) + bf2f((u16)(yB&0xffff)) + cfB*wv.x;
    float z1 = p31 + bf2f((u16)(xB>>16))    + bf2f((u16)(yB>>16))    + cfB*wv.y;
    a0 += fsilu(x0) + fsilu(z0);
    a1 += fsilu(x1) + fsilu(z1);
  }
  if (w < c) {
    int4 rA = wr[w];
    u32 xA = q1b[(size_t)rA.x*64 + lane];
    u32 yA = q2b[(size_t)rA.y*64 + lane];
    float cfA = __int_as_float(rA.z);
    float x0 = p30 + bf2f((u16)(xA&0xffff)) + bf2f((u16)(yA&0xffff)) + cfA*wv.x;
    float x1 = p31 + bf2f((u16)(xA>>16))    + bf2f((u16)(yA>>16))    + cfA*wv.y;
    a0 += fsilu(x0);
    a1 += fsilu(x1);
  }
  ((u32*)(S + (size_t)gw*128))[lane] = pk2(a0, a1);
}

// ---------------- MFMA GEMM (templated) ----------------
// MODE 0: K=448 gathered f32 A (converted) -> Q1/Q2/P3 bf16 (blockIdx.y selects; +b1 for P3)
// MODE 1: K=128 A=S(bf16),  B=WcT  -> G = sigmoid(S@Wc + cnt*bc2 + bgw)  (bf16)
// MODE 2: K=128 A=t_e2(f32),B=WgtT -> out = t_e2 + G * tanh(t_e2@wgt + bgt)  (f32)
struct GArgs {
  const float* t_f32; const float* h; const float* rbf_e2;
  const u16* rbf1p; const u16* Asrc;
  const int* src2; const int* dst2; const int* cnt;
  const u16* Bmat; const u16* Gin;
  const float* b1; const float* bgw; const float* bgt; const float* bc2;
  u16* out0; u16* out1; u16* out2;
  float* outf;
  int M;
};

template<int MODE>
__global__ __launch_bounds__(256, 2)
void k_gemm(GArgs a) {
  constexpr int KT = (MODE==0)?448:128;
  constexpr int NK = KT/32;
  __shared__ u16 As[128*40];
  __shared__ u16 Bs[128*40];
  const int tid = threadIdx.x;
  const int bm = blockIdx.x, bn = blockIdx.y;
  const int lane = tid & 63, wave = tid >> 6;
  const int wm = wave >> 1, wn = wave & 1;
  const int quad = lane >> 4, l16 = lane & 15;

  const int part = tid & 3;        // k-subchunk (8 elems)
  const int ra = tid >> 2;         // rows handled by this thread
  const int rb = ra + 64;
  long fa = (long)bm*128 + ra;
  long fb = (long)bm*128 + rb;
  if (fa >= a.M) fa = a.M-1;
  if (fb >= a.M) fb = a.M-1;
  int sa=0, da=0, sb=0, db=0;
  if constexpr (MODE==0) { sa=a.src2[fa]; da=a.dst2[fa]; sb=a.src2[fb]; db=a.dst2[fb]; }

  f32x4 acc[4][4] = {};
  for (int ks=0; ks<NK; ks++) {
    const int kb = ks*32;
    uint4 va, vb;
    if constexpr (MODE==0) {
      if (ks<4)       { va = ld8f(a.t_f32 + fa*128 + kb + part*8);
                        vb = ld8f(a.t_f32 + fb*128 + kb + part*8); }
      else if (ks<8)  { va = ld8f(a.h + (long)sa*128 + (kb-128) + part*8);
                        vb = ld8f(a.h + (long)sb*128 + (kb-128) + part*8); }
      else if (ks<12) { va = ld8f(a.h + (long)da*128 + (kb-256) + part*8);
                        vb = ld8f(a.h + (long)db*128 + (kb-256) + part*8); }
      else if (ks==12){ va = *(const uint4*)(a.rbf1p + fa*32 + part*8);
                        vb = *(const uint4*)(a.rbf1p + fb*32 + part*8); }
      else            { va = ld8f(a.rbf_e2 + fa*32 + part*8);
                        vb = ld8f(a.rbf_e2 + fb*32 + part*8); }
    } else if constexpr (MODE==1) {
      va = *(const uint4*)(a.Asrc + fa*128 + kb + part*8);
      vb = *(const uint4*)(a.Asrc + fb*128 + kb + part*8);
    } else {
      va = ld8f(a.t_f32 + fa*128 + kb + part*8);
      vb = ld8f(a.t_f32 + fb*128 + kb + part*8);
    }
    uint4 wa = *(const uint4*)(a.Bmat + (long)(bn*128 + ra)*KT + kb + part*8);
    uint4 wb = *(const uint4*)(a.Bmat + (long)(bn*128 + rb)*KT + kb + part*8);
    __syncthreads();
    *(uint4*)(As + ra*40 + part*8) = va;
    *(uint4*)(As + rb*40 + part*8) = vb;
    *(uint4*)(Bs + ra*40 + part*8) = wa;
    *(uint4*)(Bs + rb*40 + part*8) = wb;
    __syncthreads();
    bf16x8 af[4], bfr[4];
    #pragma unroll
    for (int t=0;t<4;t++) {
      af[t]  = *(const bf16x8*)(As + (wm*64 + t*16 + l16)*40 + quad*8);
      bfr[t] = *(const bf16x8*)(Bs + (wn*64 + t*16 + l16)*40 + quad*8);
    }
    #pragma unroll
    for (int tm=0;tm<4;tm++)
      #pragma unroll
      for (int tn=0;tn<4;tn++)
        acc[tm][tn] = __builtin_amdgcn_mfma_f32_16x16x32_bf16(af[tm], bfr[tn], acc[tm][tn], 0,0,0);
  }

  // epilogue (C/D: col=lane&15, row=quad*4+reg)
  #pragma unroll
  for (int tm=0;tm<4;tm++) {
    const int rloc = wm*64 + tm*16 + quad*4;
    #pragma unroll
    for (int r=0;r<4;r++) {
      long row = (long)bm*128 + rloc + r;
      if (row >= a.M) continue;
      #pragma unroll
      for (int tn=0;tn<4;tn++) {
        const int col = wn*64 + tn*16 + l16;
        float v = acc[tm][tn][r];
        if constexpr (MODE==0) {
          u16* dst = (bn==0)? a.out0 : (bn==1)? a.out1 : a.out2;
          if (bn==2) v += a.b1[col];
          dst[row*128 + col] = f2bf(v);
        } else if constexpr (MODE==1) {
          float u = v + (float)a.cnt[row]*a.bc2[col] + a.bgw[col];
          float g = 1.f/(1.f+__expf(-u));
          a.out0[row*128+col] = f2bf(g);
        } else {
          float vv = v + a.bgt[col];
          float th = 1.f - 2.f/(__expf(2.f*vv)+1.f);
          float t  = a.t_f32[row*128+col];
          float g  = bf2f(a.Gin[row*128+col]);
          a.outf[row*128+col] = t + g*th;
        }
      }
    }
  }
}

// ---------------- launch ----------------
extern "C" void kernel_launch(void* const* d_in, const int* in_sizes, int n_in,
                              void* d_out, int out_size, void* d_ws, size_t ws_size,
                              hipStream_t stream) {
  const float* t_e2  = (const float*)d_in[0];
  const float* h     = (const float*)d_in[1];
  const int* ei2     = (const int*)d_in[3];
  const int* e1_to_e2 = (const int*)d_in[4];
  const float* rbf_e1 = (const float*)d_in[7];
  const float* rbf_e2 = (const float*)d_in[8];
  const float* sph_e1 = (const float*)d_in[9];
  const float* w1  = (const float*)d_in[11];
  const float* b1  = (const float*)d_in[12];
  const float* w2  = (const float*)d_in[13];
  const float* b2  = (const float*)d_in[14];
  const float* wgw = (const float*)d_in[15];
  const float* bgw = (const float*)d_in[16];
  const float* wgt = (const float*)d_in[17];
  const float* bgt = (const float*)d_in[18];

  const int E2 = in_sizes[0]/128;
  const int Nn = in_sizes[1]/128;
  const int E1 = in_sizes[5];
  const int* src2 = ei2;
  const int* dst2 = ei2 + E2;

  // workspace carve (16B-aligned regions, ~78 MB total)
  char* p = (char*)d_ws;
  u16* Q1 = (u16*)p;       p += (size_t)E2*128*2;
  u16* Q2 = (u16*)p;       p += (size_t)E2*128*2;
  u16* P3 = (u16*)p;       p += (size_t)E2*128*2;   // aliased as S after wedge
  u16* rbf1p = (u16*)p;    p += (size_t)E2*32*2;
  u16* WbigT = (u16*)p;    p += (size_t)384*448*2;
  u16* WcT   = (u16*)p;    p += (size_t)128*128*2;
  u16* WgtT  = (u16*)p;    p += (size_t)128*128*2;
  float* sph_c = (float*)p; p += (size_t)E2*4;
  float* bc2   = (float*)p; p += 512;
  int* out_ptr = (int*)p;   p += (((size_t)(Nn+1)*4 + 63)/64)*64;
  int* cnt     = (int*)p;   p += (size_t)E2*4;
  int4* wrec   = (int4*)p;  p += (size_t)E2*8*16;
  u16* S = P3;   // alias: safe (row-local read-then-write in k_wedge2)
  u16* G = Q1;   // alias: Q1 dead after wedge stage

  hipMemsetAsync(cnt, 0, (size_t)E2*4, stream);

  k_setup_edges<<<(E1+255)/256, 256, 0, stream>>>(e1_to_e2, rbf_e1, sph_e1, rbf1p, sph_c, E1);
  k_out_ptr<<<(Nn+1+255)/256, 256, 0, stream>>>(src2, out_ptr, Nn, E2);
  k_wbigt<<<(384*448+255)/256, 256, 0, stream>>>(w1, WbigT);
  k_smallw<<<(16512+255)/256, 256, 0, stream>>>(w2, wgw, wgt, b2, WcT, WgtT, bc2);
  k_enum<<<(E2*8+255)/256, 256, 0, stream>>>(src2, dst2, out_ptr, sph_c, wrec, cnt, E2);

  const int Mb = (E2+127)/128;
  {
    GArgs a = {};
    a.t_f32=t_e2; a.h=h; a.rbf1p=rbf1p; a.rbf_e2=rbf_e2;
    a.src2=src2; a.dst2=dst2; a.Bmat=WbigT; a.b1=b1;
    a.out0=Q1; a.out1=Q2; a.out2=P3; a.M=E2;
    k_gemm<0><<<dim3(Mb,3), 256, 0, stream>>>(a);
  }
  k_wedge2<<<(E2+3)/4, 256, 0, stream>>>(Q1, Q2, P3, wrec, cnt, w1, S, E2);
  {
    GArgs a = {};
    a.Asrc=S; a.cnt=cnt; a.Bmat=WcT; a.bgw=bgw; a.bc2=bc2;
    a.out0=G; a.M=E2;
    k_gemm<1><<<dim3(Mb,1), 256, 0, stream>>>(a);
  }
  {
    GArgs a = {};
    a.t_f32=t_e2; a.Bmat=WgtT; a.bgt=bgt; a.Gin=G;
    a.outf=(float*)d_out; a.M=E2;
    k_gemm<2><<<dim3(Mb,1), 256, 0, stream>>>(a);
  }
}